// Round 1
// 128.816 us; speedup vs baseline: 1.0209x; 1.0209x over previous
//
#include <hip/hip_runtime.h>

#define F_DIM   128
#define C_DIM   100000
#define B_ROWS  512
#define ANGLE   0.5f
#define CPB     128            // classes per block
#define NCB     782            // ceil(100000/128); last block has 96 OOB pad classes
#define OOB_PAD 96.0f          // pad classes contribute exp(0)=1 each to row sums
#define LOG2E   1.4426950408889634f

typedef __attribute__((ext_vector_type(4))) float        f32x4;
typedef __attribute__((ext_vector_type(8))) short        bf16x8;
typedef __attribute__((ext_vector_type(4))) unsigned int u32x4;

// packed fp32->bf16 (RNE), 2 elements per instruction
static __device__ __forceinline__ unsigned int pk2(float a, float b) {
    unsigned int r;
    asm("v_cvt_pk_bf16_f32 %0, %1, %2" : "=v"(r) : "v"(a), "v"(b));
    return r;
}

// ---------------------------------------------------------------------------
// arc_main: block = 8 waves = 128 classes x 256 batch rows. grid (782, 2).
//   w staged via 8x f32x4 loads/thread (thread = 4 classes x 8 ks), packed
//   with v_cvt_pk_bf16_f32, scaled by log2e so the exp becomes native exp2.
//   LDS swizzle f(cls) = (cls&12) | ((cls^(cls>>4))&3): conflict-free for
//   BOTH the stride-4-class write phase and consecutive-class read phase.
//   w staged first (32 regs released before fB built -> ~60 VGPR peak).
// ---------------------------------------------------------------------------
__global__ __launch_bounds__(512, 4)
void arc_main(const float* __restrict__ feat,
              const float* __restrict__ w,
              float* __restrict__ pp)        // [B_ROWS][NCB]
{
    __shared__ unsigned short lBt[128 * 128];   // [c][k] swizzled, 32 KB

    const int tid  = threadIdx.x;
    const int cb   = blockIdx.x;
    const int c0   = cb * CPB;
    const int r0   = blockIdx.y * 256;
    const int lane = tid & 63;
    const int wv   = tid >> 6;                // 0..7 -> 32-batch strip
    const int quad = lane >> 4;
    const int l15  = lane & 15;

    // ---- stage w^T tile (scaled by log2e): thread = (class-quad, k-octet) ----
    {
        const int cq = tid & 31;              // classes cq*4 .. cq*4+3
        const int ko = tid >> 5;              // ks ko*8 .. ko*8+7
        const int gc = c0 + cq * 4;
        f32x4 wr[8];
        if (gc < C_DIM) {                     // whole quad valid (C%4==0)
            const float* wp = w + (size_t)ko * 8 * C_DIM + gc;
            #pragma unroll
            for (int i = 0; i < 8; ++i)
                wr[i] = *(const f32x4*)(wp + (size_t)i * C_DIM);
        } else {
            #pragma unroll
            for (int i = 0; i < 8; ++i)
                wr[i] = (f32x4){0.f, 0.f, 0.f, 0.f};
        }
        #pragma unroll
        for (int j = 0; j < 4; ++j) {
            const int cls = cq * 4 + j;
            union { u32x4 u; bf16x8 h; } c;
            c.u[0] = pk2(wr[0][j] * LOG2E, wr[1][j] * LOG2E);
            c.u[1] = pk2(wr[2][j] * LOG2E, wr[3][j] * LOG2E);
            c.u[2] = pk2(wr[4][j] * LOG2E, wr[5][j] * LOG2E);
            c.u[3] = pk2(wr[6][j] * LOG2E, wr[7][j] * LOG2E);
            const int f = (cls & 12) | ((cls ^ (cls >> 4)) & 3);
            *(bf16x8*)&lBt[cls * 128 + ((ko ^ f) << 3)] = c.h;
        }
    }

    // ---- feat fragments (registers; LDS-independent, fills pre-barrier gap) ----
    // fB[s][ks] = f[b][k0..k0+7], b = r0+wv*32+s*16+l15, k0 = ks*32+quad*8
    bf16x8 fB[2][4];
    #pragma unroll
    for (int s = 0; s < 2; ++s) {
        const int b = r0 + wv * 32 + s * 16 + l15;
        #pragma unroll
        for (int ks = 0; ks < 4; ++ks) {
            const int k0 = ks * 32 + quad * 8;
            const f32x4 u0 = *(const f32x4*)(feat + b * F_DIM + k0);
            const f32x4 u1 = *(const f32x4*)(feat + b * F_DIM + k0 + 4);
            union { u32x4 u; bf16x8 h; } c;
            c.u[0] = pk2(u0[0], u0[1]); c.u[1] = pk2(u0[2], u0[3]);
            c.u[2] = pk2(u1[0], u1[1]); c.u[3] = pk2(u1[2], u1[3]);
            fB[s][ks] = c.h;
        }
    }
    __syncthreads();

    // ---- MFMA + exp2: 8 parallel accumulators (chain length 8 each) ----
    float eA0 = 0.f, eA1 = 0.f, eA2 = 0.f, eA3 = 0.f;   // s=0 batch col
    float eB0 = 0.f, eB1 = 0.f, eB2 = 0.f, eB3 = 0.f;   // s=1 batch col
    #pragma unroll
    for (int m = 0; m < 8; ++m) {
        f32x4 a0 = {0.f, 0.f, 0.f, 0.f};
        f32x4 a1 = {0.f, 0.f, 0.f, 0.f};
        const int rb = (m * 16 + l15) * 128;
        const int fr = (l15 & 12) | ((l15 ^ m) & 3);   // == f(row), row=m*16+l15
        #pragma unroll
        for (int ks = 0; ks < 4; ++ks) {
            const int pc = (ks * 4 + quad) ^ fr;
            const bf16x8 af = *(const bf16x8*)&lBt[rb + (pc << 3)];
            a0 = __builtin_amdgcn_mfma_f32_16x16x32_bf16(af, fB[0][ks], a0, 0, 0, 0);
            a1 = __builtin_amdgcn_mfma_f32_16x16x32_bf16(af, fB[1][ks], a1, 0, 0, 0);
        }
        eA0 += __builtin_amdgcn_exp2f(a0[0]); eA1 += __builtin_amdgcn_exp2f(a0[1]);
        eA2 += __builtin_amdgcn_exp2f(a0[2]); eA3 += __builtin_amdgcn_exp2f(a0[3]);
        eB0 += __builtin_amdgcn_exp2f(a1[0]); eB1 += __builtin_amdgcn_exp2f(a1[1]);
        eB2 += __builtin_amdgcn_exp2f(a1[2]); eB3 += __builtin_amdgcn_exp2f(a1[3]);
    }

    float esum0 = (eA0 + eA1) + (eA2 + eA3);
    float esum1 = (eB0 + eB1) + (eB2 + eB3);
    // reduce across quads (same batch col holds different class rows)
    esum0 += __shfl_xor(esum0, 16); esum0 += __shfl_xor(esum0, 32);
    esum1 += __shfl_xor(esum1, 16); esum1 += __shfl_xor(esum1, 32);
    if (lane < 16) {
        const int r = r0 + wv * 32 + lane;
        pp[(size_t)r * NCB + cb]        = esum0;   // transposed: coalesced reduce
        pp[(size_t)(r + 16) * NCB + cb] = esum1;
    }
}

// ---------------------------------------------------------------------------
// arc_row: exact fp32 target-column terms + coalesced row-sum. One wave/row.
// ---------------------------------------------------------------------------
__global__ void arc_row(const float* __restrict__ feat,
                        const float* __restrict__ w,
                        const int*   __restrict__ target,
                        const float* __restrict__ pp,
                        float* __restrict__ term)
{
    const int b    = blockIdx.x;
    const int lane = threadIdx.x;             // 64
    const int t    = target[b];

    float dot = 0.f, wsq = 0.f, fsq = 0.f, rs = 0.f;
    #pragma unroll
    for (int h = 0; h < 2; ++h) {
        const int f   = lane + h * 64;
        const float fv = feat[b * F_DIM + f];
        const float wc = w[(size_t)f * C_DIM + t];
        dot += fv * wc;
        wsq += wc * wc;
        fsq += fv * fv;
    }
    #pragma unroll
    for (int j = 0; j < 13; ++j) {            // 13*64 >= 782, coalesced L2 hits
        const int c = lane + j * 64;
        if (c < NCB) rs += pp[(size_t)b * NCB + c];
    }

    #pragma unroll
    for (int off = 32; off > 0; off >>= 1) {
        dot += __shfl_xor(dot, off);
        wsq += __shfl_xor(wsq, off);
        fsq += __shfl_xor(fsq, off);
        rs  += __shfl_xor(rs,  off);
    }
    if (lane == 0) {
        const float mod = sqrtf(fsq) * sqrtf(wsq);
        float ct = dot / (mod * 1.01f);
        ct = fminf(1.f, fmaxf(-1.f, ct));
        const float th   = acosf(ct) + ANGLE;
        const float marg = mod * cosf(th);
        const float down = rs - OOB_PAD - expf(dot) + expf(marg);
        term[b] = marg - logf(down);
    }
}

// ---------------------------------------------------------------------------
__global__ void arc_loss(const float* __restrict__ term,
                         float* __restrict__ out)
{
    __shared__ float red[B_ROWS];
    const int b = threadIdx.x;
    red[b] = term[b];
    __syncthreads();
    #pragma unroll
    for (int st = 256; st > 0; st >>= 1) {
        if (b < st) red[b] += red[b + st];
        __syncthreads();
    }
    if (b == 0) out[0] = -red[0] / (float)B_ROWS;
}

// ---------------------------------------------------------------------------
extern "C" void kernel_launch(void* const* d_in, const int* in_sizes, int n_in,
                              void* d_out, int out_size, void* d_ws, size_t ws_size,
                              hipStream_t stream)
{
    const float* feat   = (const float*)d_in[0];   // [512,128] fp32
    const float* w      = (const float*)d_in[1];   // [128,100000] fp32
    const int*   target = (const int*)d_in[2];     // [512]

    float* pp   = (float*)d_ws;                    // [512][782], fully overwritten
    float* term = pp + (size_t)B_ROWS * NCB;       // [512]

    arc_main<<<dim3(NCB, 2), 512, 0, stream>>>(feat, w, pp);
    arc_row<<<B_ROWS, 64, 0, stream>>>(feat, w, target, pp, term);
    arc_loss<<<1, B_ROWS, 0, stream>>>(term, (float*)d_out);
}